// Round 2
// baseline (539.484 us; speedup 1.0000x reference)
//
#include <hip/hip_runtime.h>
#include <math.h>

// out[i, j, k] = K[j, k] * a[i, k],  K[j, m] = exp(-GAMMA * ||a_j - b_m||^2)
// N = 1024, M = D = 128. rotation/entangle params are dead (softmax over a
// length-1 axis == 1). Output = 512 MiB fp32 -> pure write-BW problem.
//
// Fused single kernel: block = (K-row j, 256-row i-tile).
//   Phase 1: recompute K row j (128 dots of length 128) into LDS -- ~16K FMA,
//            negligible; removes the separate kernel + K HBM round-trip.
//   Phase 2: kv is LOOP-INVARIANT in registers (k4 = tid&31 fixed per thread);
//            inner loop = cached a4 load -> 4 muls -> nontemporal 16B store,
//            32 iters/thread, unroll 8 -> many stores in flight per thread.
// 4096 blocks x 256 threads; each block writes 128 KiB (full 512 B lines).

#define GAMMA_F 1.0f
#define N_ROWS  1024
#define DIM     128
#define I_TILE  256
#define N_ITILE (N_ROWS / I_TILE)   // 4
#define THREADS 256

// native clang vector type: accepted by __builtin_nontemporal_store
typedef float floatx4 __attribute__((ext_vector_type(4)));

__global__ __launch_bounds__(THREADS) void fused_bcast_kernel(
    const float* __restrict__ a,
    const float* __restrict__ b,
    floatx4* __restrict__ out4)
{
    __shared__ float4 a_sh[DIM / 4];   // a row j (512 B)
    __shared__ float  k_row[DIM];      // K row j (512 B)

    const int bid = blockIdx.x;
    const int j   = bid >> 2;               // 0..1023  (K row)
    const int i0  = (bid & 3) * I_TILE;     // 0,256,512,768
    const int tid = threadIdx.x;

    // ---- stage a_j into LDS (float4, coalesced) ----
    if (tid < DIM / 4) {
        a_sh[tid] = reinterpret_cast<const float4*>(a + (size_t)j * DIM)[tid];
    }
    __syncthreads();

    // ---- phase 1: threads 0..127 compute K[j, m] (bit-identical to old kernel) ----
    if (tid < DIM) {
        const float4* b4 = reinterpret_cast<const float4*>(b + (size_t)tid * DIM);
        float acc = 0.0f;
#pragma unroll 8
        for (int d = 0; d < DIM / 4; ++d) {
            const float4 av = a_sh[d];
            const float4 bv = b4[d];
            const float dx = av.x - bv.x;
            const float dy = av.y - bv.y;
            const float dz = av.z - bv.z;
            const float dw = av.w - bv.w;
            acc = fmaf(dx, dx, acc);
            acc = fmaf(dy, dy, acc);
            acc = fmaf(dz, dz, acc);
            acc = fmaf(dw, dw, acc);
        }
        k_row[tid] = expf(-GAMMA_F * acc);
    }
    __syncthreads();

    // ---- phase 2: stream out[i, j, :] for i in [i0, i0+I_TILE) ----
    const int k4 = tid & 31;   // which float4 of the 128-float row
    const int ir = tid >> 5;   // 0..7: i-row within an 8-row group
    const floatx4 kv = reinterpret_cast<const floatx4*>(k_row)[k4];  // loop-invariant

    const floatx4* __restrict__ a4 = reinterpret_cast<const floatx4*>(a);
    const int i_base = i0 + ir;
    size_t o_idx = ((size_t)i_base * N_ROWS + j) * (DIM / 4) + k4;
    size_t a_idx = (size_t)i_base * (DIM / 4) + k4;

    const size_t o_step = (size_t)8 * N_ROWS * (DIM / 4);  // 8 i-rows of output
    const size_t a_step = (size_t)8 * (DIM / 4);           // 8 i-rows of a

#pragma unroll 8
    for (int it = 0; it < I_TILE / 8; ++it) {
        const floatx4 av = a4[a_idx + (size_t)it * a_step];
        const floatx4 o  = av * kv;
        __builtin_nontemporal_store(o, &out4[o_idx + (size_t)it * o_step]);
    }
}

extern "C" void kernel_launch(void* const* d_in, const int* in_sizes, int n_in,
                              void* d_out, int out_size, void* d_ws, size_t ws_size,
                              hipStream_t stream)
{
    const float* a = reinterpret_cast<const float*>(d_in[0]);   // [1024, 128]
    const float* b = reinterpret_cast<const float*>(d_in[1]);   // [128, 128]
    // d_in[2], d_in[3] (rotation/entangle params) are mathematically dead.

    fused_bcast_kernel<<<N_ROWS * N_ITILE, THREADS, 0, stream>>>(
        a, b, reinterpret_cast<floatx4*>(d_out));
}

// Round 3
// 455.020 us; speedup vs baseline: 1.1856x; 1.1856x over previous
//
#include <hip/hip_runtime.h>
#include <math.h>

// out[i, j, k] = K[j, k] * a[i, k],  K[j, m] = exp(-GAMMA * ||a_j - b_m||^2)
// N = 1024, M = D = 128. rotation/entangle params dead (softmax over len-1 axis).
// Output = 512 MiB fp32 -> pure write-BW problem. The harness's own poison
// fill sustains 6.33 TB/s with fully LINEAR plain stores; this version makes
// phase 2 structurally identical to that fill:
//   - each block writes one contiguous 64 KB span (16 float4/thread, unrolled)
//   - consecutive blocks -> consecutive spans (perfect DRAM page locality)
//   - plain stores (not nontemporal), 256-thread blocks, 8192 blocks
//   - av loop-invariant in a register; kv streams from L2-resident K (512 KB)

#define GAMMA_F 1.0f
#define N_ROWS  1024
#define DIM     128

typedef float floatx4 __attribute__((ext_vector_type(4)));

// ---------------------------------------------------------------------------
// Kernel 1: K[j, m] = exp(-||a_j - b_m||^2).  grid = 1024 blocks, 128 threads.
// (verified round-0 kernel, bit-identical arithmetic)
// ---------------------------------------------------------------------------
__global__ __launch_bounds__(DIM) void compute_K_kernel(
    const float* __restrict__ a,
    const float* __restrict__ b,
    float* __restrict__ K)
{
    __shared__ float4 a_sh[DIM / 4];
    const int j = blockIdx.x;
    const int m = threadIdx.x;

    if (m < DIM / 4) {
        a_sh[m] = reinterpret_cast<const float4*>(a + (size_t)j * DIM)[m];
    }
    __syncthreads();

    const float4* b4 = reinterpret_cast<const float4*>(b + (size_t)m * DIM);
    float acc = 0.0f;
#pragma unroll 8
    for (int d = 0; d < DIM / 4; ++d) {
        const float4 av = a_sh[d];
        const float4 bv = b4[d];
        const float dx = av.x - bv.x;
        const float dy = av.y - bv.y;
        const float dz = av.z - bv.z;
        const float dw = av.w - bv.w;
        acc = fmaf(dx, dx, acc);
        acc = fmaf(dy, dy, acc);
        acc = fmaf(dz, dz, acc);
        acc = fmaf(dw, dw, acc);
    }
    K[(size_t)j * DIM + m] = expf(-GAMMA_F * acc);
}

// ---------------------------------------------------------------------------
// Kernel 2: linear streaming multiply, fill-shaped.
//   flat float4 index v = bid*4096 + tid + it*256, it = 0..15
//   k4 = v & 31  = tid & 31          (invariant: 256 % 32 == 0)
//   i  = v >> 15 = bid >> 3          (constant per block)
//   j  = (v>>5) & 1023 = (bid&7)*128 + (tid>>5) + it*8
// Each block writes contiguous [bid*64KB, (bid+1)*64KB). 8192 blocks total.
// ---------------------------------------------------------------------------
__global__ __launch_bounds__(256) void stream_mul_kernel(
    const floatx4* __restrict__ a4,
    const floatx4* __restrict__ K4,
    floatx4* __restrict__ out4)
{
    const unsigned tid  = threadIdx.x;
    const unsigned bid  = blockIdx.x;
    const unsigned base = bid * 4096u;            // float4 units, 64 KB/block

    const unsigned k4 = tid & 31u;
    const unsigned i  = bid >> 3;                 // 8 blocks per i-slab (512 KB)
    const floatx4 av  = a4[i * 32u + k4];         // loop-invariant

    const unsigned j0 = (bid & 7u) * 128u + (tid >> 5);
    const unsigned v0 = base + tid;

#pragma unroll
    for (int it = 0; it < 16; ++it) {
        const floatx4 kv = K4[(j0 + (unsigned)it * 8u) * 32u + k4];
        out4[v0 + (unsigned)it * 256u] = av * kv;   // plain store, like the fill
    }
}

extern "C" void kernel_launch(void* const* d_in, const int* in_sizes, int n_in,
                              void* d_out, int out_size, void* d_ws, size_t ws_size,
                              hipStream_t stream)
{
    const float* a = reinterpret_cast<const float*>(d_in[0]);   // [1024, 128]
    const float* b = reinterpret_cast<const float*>(d_in[1]);   // [128, 128]
    // d_in[2], d_in[3] (rotation/entangle params) are mathematically dead.

    float* K = reinterpret_cast<float*>(d_ws);                  // [1024,128] scratch

    compute_K_kernel<<<N_ROWS, DIM, 0, stream>>>(a, b, K);

    const unsigned n_vec4  = (unsigned)(out_size / 16);         // 33,554,432 float4
    const unsigned nblocks = n_vec4 / 4096u;                    // 8192
    stream_mul_kernel<<<nblocks, 256, 0, stream>>>(
        reinterpret_cast<const floatx4*>(a),
        reinterpret_cast<const floatx4*>(K),
        reinterpret_cast<floatx4*>(d_out));
}